// Round 14
// baseline (333.587 us; speedup 1.0000x reference)
//
#include <hip/hip_runtime.h>
#include <hip/hip_fp8.h>

#define DIM 128
#define LN_EPS 1e-5f

typedef __attribute__((ext_vector_type(8))) short s16x8;   // 8 bf16 in 4 VGPRs
typedef __attribute__((ext_vector_type(4))) float f32x4;
typedef __attribute__((ext_vector_type(2))) float f32x2;
typedef __attribute__((ext_vector_type(4))) unsigned int u32x4;

__device__ __forceinline__ unsigned short f2bf(float f) {
    unsigned u = __float_as_uint(f);
    unsigned r = u + 0x7fffu + ((u >> 16) & 1u);   // round-to-nearest-even
    return (unsigned short)(r >> 16);
}
__device__ __forceinline__ float bf2f(unsigned short b) {
    return __uint_as_float(((unsigned)b) << 16);
}
__device__ __forceinline__ unsigned char f2fp8(float f) {
    return (unsigned char)__hip_cvt_float_to_fp8(f, __HIP_SATFINITE, __HIP_E4M3);
}
// accumulate 4 fp8 bytes (linear col order) into a[0..3]
__device__ __forceinline__ void acc_fp8x4(float* a, unsigned v) {
    f32x2 lo = __builtin_amdgcn_cvt_pk_f32_fp8(v, false);  // bytes 0,1
    f32x2 hi = __builtin_amdgcn_cvt_pk_f32_fp8(v, true);   // bytes 2,3
    a[0] += lo[0]; a[1] += lo[1]; a[2] += hi[0]; a[3] += hi[1];
}
// accumulate a full u32x4 (16 fp8 bytes) into a[0..15]
__device__ __forceinline__ void acc_fp8x16(float* a, u32x4 v) {
    acc_fp8x4(a + 0,  v[0]);
    acc_fp8x4(a + 4,  v[1]);
    acc_fp8x4(a + 8,  v[2]);
    acc_fp8x4(a + 12, v[3]);
}

// ---------------- prep: weight cvt (f32 -> bf16 transposed) + degree count ----------------

__global__ __launch_bounds__(256) void prep(const float* __restrict__ in_w,
                                            const float* __restrict__ w1,
                                            const float* __restrict__ w2,
                                            unsigned short* __restrict__ wt, int L,
                                            const int* __restrict__ dst, int E,
                                            int* __restrict__ counts, int nWblk) {
    if ((int)blockIdx.x < nWblk) {
        int mat = blockIdx.x >> 3, part = blockIdx.x & 7;
        const float* src;
        if (mat == 0) src = in_w;
        else if (mat <= L) src = w1 + (size_t)(mat - 1) * DIM * DIM;
        else src = w2 + (size_t)(mat - 1 - L) * DIM * DIM;
        unsigned short* dstw = wt + (size_t)mat * DIM * DIM;
        int base = part * 2048 + threadIdx.x;
#pragma unroll
        for (int j = 0; j < 8; ++j) {
            int i = base + j * 256;
            int k = i >> 7, n = i & 127;
            dstw[n * DIM + k] = f2bf(src[i]);
        }
    } else {
        int b = blockIdx.x - nWblk;
        int i = (b * 256 + threadIdx.x) * 4;
        if (i + 3 < E) {
            int4 d = *(const int4*)(dst + i);
            atomicAdd(&counts[d.x], 1);
            atomicAdd(&counts[d.y], 1);
            atomicAdd(&counts[d.z], 1);
            atomicAdd(&counts[d.w], 1);
        } else {
            for (int j = i; j < E; ++j) atomicAdd(&counts[dst[j]], 1);
        }
    }
}

// ---------------- scan (single dispatch): block offset computed in-block ----------------

__global__ __launch_bounds__(256) void scan_all(const int* __restrict__ counts, int n,
                                                int* __restrict__ rowptr,
                                                int* __restrict__ cursor,
                                                float* __restrict__ dinv, int E) {
    __shared__ int wsum[4];
    int tid = threadIdx.x;
    int lane = tid & 63, wid = tid >> 6;

    int limit = blockIdx.x * 1024;            // multiple of 1024
    int acc = 0;
    for (int i = tid * 4; i < limit; i += 1024) {
        int4 c4 = *(const int4*)(counts + i);
        acc += c4.x + c4.y + c4.z + c4.w;
    }
#pragma unroll
    for (int off = 32; off > 0; off >>= 1) acc += __shfl_xor(acc, off, 64);
    if (lane == 0) wsum[wid] = acc;
    __syncthreads();
    int bofs = wsum[0] + wsum[1] + wsum[2] + wsum[3];
    __syncthreads();                          // wsum reused below

    if (blockIdx.x == 0 && tid == 0) rowptr[n] = E;

    int base = blockIdx.x * 1024 + tid * 4;
    int v[4];
#pragma unroll
    for (int j = 0; j < 4; ++j) {
        int i = base + j;
        v[j] = (i < n) ? counts[i] : 0;
    }
    int tsum = v[0] + v[1] + v[2] + v[3];
    int incl = tsum;
#pragma unroll
    for (int off = 1; off < 64; off <<= 1) {
        int t = __shfl_up(incl, off, 64);
        if (lane >= off) incl += t;
    }
    if (lane == 63) wsum[wid] = incl;
    __syncthreads();
    int wofs = 0;
    for (int w = 0; w < 4; ++w)
        if (w < wid) wofs += wsum[w];
    int excl = bofs + wofs + (incl - tsum);
#pragma unroll
    for (int j = 0; j < 4; ++j) {
        int i = base + j;
        if (i < n) {
            rowptr[i] = excl;
            cursor[i] = excl;
            dinv[i] = 1.0f / (float)((v[j] > 1) ? v[j] : 1);
            excl += v[j];
        }
    }
}

// ---------------- CSR fill ----------------

__global__ void fill_csr(const int* __restrict__ src, const int* __restrict__ dst, int E,
                         int* __restrict__ cursor, unsigned short* __restrict__ srcidx) {
    int i = (blockIdx.x * 256 + threadIdx.x) * 4;
    if (i + 3 < E) {
        int4 s4 = *(const int4*)(src + i);
        int4 d4 = *(const int4*)(dst + i);
        int p0 = atomicAdd(&cursor[d4.x], 1); srcidx[p0] = (unsigned short)s4.x;
        int p1 = atomicAdd(&cursor[d4.y], 1); srcidx[p1] = (unsigned short)s4.y;
        int p2 = atomicAdd(&cursor[d4.z], 1); srcidx[p2] = (unsigned short)s4.z;
        int p3 = atomicAdd(&cursor[d4.w], 1); srcidx[p3] = (unsigned short)s4.w;
    } else {
        for (int j = i; j < E; ++j) {
            int p = atomicAdd(&cursor[dst[j]], 1);
            srcidx[p] = (unsigned short)src[j];
        }
    }
}

// ---------------- input projection: 32 rows/block, LDS-transposed epilogue ----------
// (round-10 form, verified bit-exact)

__global__ __launch_bounds__(256) void gemm_bias32(const float* __restrict__ x,
                                                   const unsigned short* __restrict__ Wt,
                                                   const float* __restrict__ bias,
                                                   unsigned short* __restrict__ hb,
                                                   unsigned char* __restrict__ h8, int N) {
    __shared__ __align__(16) unsigned short X[32][136];
    __shared__ __align__(16) float Z[32][132];
    __shared__ __align__(16) float bias_s[128];

    int tid = threadIdx.x;
    int w = tid >> 6, lane = tid & 63;
    int quad = lane >> 4, l16 = lane & 15;
    int r0 = blockIdx.x * 32;
    int cs = w * 32;

    // ---- stage bias (128 f32) ----
    if (tid < 32) *(float4*)(bias_s + tid * 4) = *(const float4*)(bias + tid * 4);

    // ---- stage x tile: thread covers row (tid>>3), cols [(tid&7)*16, +16) ----
    {
        int row = tid >> 3;
        int c0 = (tid & 7) * 16;
        int grow = r0 + row;
        u32x4 o0 = {0, 0, 0, 0}, o1 = {0, 0, 0, 0};
        if (grow < N) {
            const float4* xp = (const float4*)(x + ((size_t)grow << 7) + c0);
            float4 f0 = xp[0], f1 = xp[1], f2 = xp[2], f3 = xp[3];
            o0[0] = (unsigned)f2bf(f0.x) | ((unsigned)f2bf(f0.y) << 16);
            o0[1] = (unsigned)f2bf(f0.z) | ((unsigned)f2bf(f0.w) << 16);
            o0[2] = (unsigned)f2bf(f1.x) | ((unsigned)f2bf(f1.y) << 16);
            o0[3] = (unsigned)f2bf(f1.z) | ((unsigned)f2bf(f1.w) << 16);
            o1[0] = (unsigned)f2bf(f2.x) | ((unsigned)f2bf(f2.y) << 16);
            o1[1] = (unsigned)f2bf(f2.z) | ((unsigned)f2bf(f2.w) << 16);
            o1[2] = (unsigned)f2bf(f3.x) | ((unsigned)f2bf(f3.y) << 16);
            o1[3] = (unsigned)f2bf(f3.z) | ((unsigned)f2bf(f3.w) << 16);
        }
        *(u32x4*)(&X[row][c0])     = o0;
        *(u32x4*)(&X[row][c0 + 8]) = o1;
    }
    __syncthreads();

    // ---- GEMM: wave computes 32 rows x 32 cols, B-frags shared ----
    f32x4 ac[2][2];
    ac[0][0] = (f32x4){0.f, 0.f, 0.f, 0.f}; ac[0][1] = (f32x4){0.f, 0.f, 0.f, 0.f};
    ac[1][0] = (f32x4){0.f, 0.f, 0.f, 0.f}; ac[1][1] = (f32x4){0.f, 0.f, 0.f, 0.f};
#pragma unroll
    for (int k0 = 0; k0 < 128; k0 += 32) {
        s16x8 b0 = *(const s16x8*)(Wt + ((size_t)(cs + l16) << 7) + quad * 8 + k0);
        s16x8 b1 = *(const s16x8*)(Wt + ((size_t)(cs + 16 + l16) << 7) + quad * 8 + k0);
        s16x8 a0 = *(const s16x8*)(&X[l16][quad * 8 + k0]);
        s16x8 a1 = *(const s16x8*)(&X[16 + l16][quad * 8 + k0]);
        ac[0][0] = __builtin_amdgcn_mfma_f32_16x16x32_bf16(a0, b0, ac[0][0], 0, 0, 0);
        ac[0][1] = __builtin_amdgcn_mfma_f32_16x16x32_bf16(a0, b1, ac[0][1], 0, 0, 0);
        ac[1][0] = __builtin_amdgcn_mfma_f32_16x16x32_bf16(a1, b0, ac[1][0], 0, 0, 0);
        ac[1][1] = __builtin_amdgcn_mfma_f32_16x16x32_bf16(a1, b1, ac[1][1], 0, 0, 0);
    }

    // ---- dump acc+bias to LDS Z (fragment scatter stays in LDS) ----
#pragma unroll
    for (int rt = 0; rt < 2; ++rt) {
#pragma unroll
        for (int c = 0; c < 2; ++c) {
            int col = cs + c * 16 + l16;
            float bv = bias_s[col];
#pragma unroll
            for (int reg = 0; reg < 4; ++reg) {
                Z[rt * 16 + quad * 4 + reg][col] = ac[rt][c][reg] + bv;
            }
        }
    }
    __syncthreads();

    // ---- pass 2: row-contiguous vector stores ----
    {
        int row = tid >> 3;
        int c0 = (tid & 7) * 16;
        int grow = r0 + row;
        if (grow < N) {
            u32x4 ob0, ob1, o8;
#pragma unroll
            for (int j = 0; j < 4; ++j) {
                float v0 = Z[row][c0 + 2 * j];
                float v1 = Z[row][c0 + 2 * j + 1];
                float v2 = Z[row][c0 + 8 + 2 * j];
                float v3 = Z[row][c0 + 8 + 2 * j + 1];
                ob0[j] = (unsigned)f2bf(v0) | ((unsigned)f2bf(v1) << 16);
                ob1[j] = (unsigned)f2bf(v2) | ((unsigned)f2bf(v3) << 16);
                float w0 = Z[row][c0 + 4 * j], w1 = Z[row][c0 + 4 * j + 1];
                float w2 = Z[row][c0 + 4 * j + 2], w3 = Z[row][c0 + 4 * j + 3];
                o8[j] = (unsigned)f2fp8(w0) | ((unsigned)f2fp8(w1) << 8)
                      | ((unsigned)f2fp8(w2) << 16) | ((unsigned)f2fp8(w3) << 24);
            }
            *(u32x4*)(hb + ((size_t)grow << 7) + c0)     = ob0;
            *(u32x4*)(hb + ((size_t)grow << 7) + c0 + 8) = ob1;
            *(u32x4*)(h8 + ((size_t)grow << 7) + c0)     = o8;
        }
    }
}

// ---------------- aggregation-only kernel (round-4 form, ushort srcidx) ----------------

__global__ __launch_bounds__(256) void aggregate(const unsigned char* __restrict__ h8in,
                                                 const int* __restrict__ rowptr,
                                                 const unsigned short* __restrict__ srcidx,
                                                 const float* __restrict__ dinv,
                                                 unsigned short* __restrict__ mout, int N) {
    int tid = threadIdx.x;
    int w = tid >> 6, lane = tid & 63;
    int g = lane >> 3, li = lane & 7;
    int nd = blockIdx.x * 32 + w * 8 + g;
    bool nv = nd < N;

    int e  = nv ? rowptr[nd] : 0;
    int ee = nv ? rowptr[nd + 1] : 0;
    float di = nv ? dinv[nd] : 0.f;

    const unsigned char* hsl = h8in + li * 16;   // lane's 16-B slice of a row

    float a[16];
#pragma unroll
    for (int j = 0; j < 16; ++j) a[j] = 0.f;

#define GIDX(jj) (((jj) < ee) ? (int)srcidx[(jj)] : -1)
    int jA = e;
    int iA0 = GIDX(jA + 0), iA1 = GIDX(jA + 1), iA2 = GIDX(jA + 2), iA3 = GIDX(jA + 3);
    u32x4 A0 = {0, 0, 0, 0}, A1 = {0, 0, 0, 0}, A2 = {0, 0, 0, 0}, A3 = {0, 0, 0, 0};
    if (iA0 >= 0) A0 = *(const u32x4*)(hsl + ((size_t)iA0 << 7));
    if (iA1 >= 0) A1 = *(const u32x4*)(hsl + ((size_t)iA1 << 7));
    if (iA2 >= 0) A2 = *(const u32x4*)(hsl + ((size_t)iA2 << 7));
    if (iA3 >= 0) A3 = *(const u32x4*)(hsl + ((size_t)iA3 << 7));
    int jB = jA + 4;
    int iB0 = GIDX(jB + 0), iB1 = GIDX(jB + 1), iB2 = GIDX(jB + 2), iB3 = GIDX(jB + 3);

    while (__any(jA < ee)) {
        u32x4 B0 = {0, 0, 0, 0}, B1v = {0, 0, 0, 0}, B2v = {0, 0, 0, 0}, B3 = {0, 0, 0, 0};
        if (iB0 >= 0) B0  = *(const u32x4*)(hsl + ((size_t)iB0 << 7));
        if (iB1 >= 0) B1v = *(const u32x4*)(hsl + ((size_t)iB1 << 7));
        if (iB2 >= 0) B2v = *(const u32x4*)(hsl + ((size_t)iB2 << 7));
        if (iB3 >= 0) B3  = *(const u32x4*)(hsl + ((size_t)iB3 << 7));
        int jC = jB + 4;
        int iC0 = GIDX(jC + 0), iC1 = GIDX(jC + 1), iC2 = GIDX(jC + 2), iC3 = GIDX(jC + 3);
        acc_fp8x16(a, A0);
        acc_fp8x16(a, A1);
        acc_fp8x16(a, A2);
        acc_fp8x16(a, A3);
        jA = jB; A0 = B0; A1 = B1v; A2 = B2v; A3 = B3;
        jB = jC; iB0 = iC0; iB1 = iC1; iB2 = iC2; iB3 = iC3;
    }
#undef GIDX

    if (nv) {
        u32x4 o0, o1;
#pragma unroll
        for (int j = 0; j < 4; ++j) {
            unsigned lo0 = f2bf(a[2 * j]     * di);
            unsigned hi0 = f2bf(a[2 * j + 1] * di);
            o0[j] = lo0 | (hi0 << 16);
            unsigned lo1 = f2bf(a[8 + 2 * j]     * di);
            unsigned hi1 = f2bf(a[8 + 2 * j + 1] * di);
            o1[j] = lo1 | (hi1 << 16);
        }
        unsigned short* mp = mout + ((size_t)nd << 7) + li * 16;
        *(u32x4*)(mp)     = o0;
        *(u32x4*)(mp + 8) = o1;
    }
}

// ---------------- MLP + LN kernel: r8 structure minus the m-staging phase ----------
// (round-13 form — wave mapping, P transpose, epilogue, reduction tree, stores
// byte-identical to round-8; GEMM1 A-fragments load directly from global m.)

__global__ __launch_bounds__(256) void mlp_ln(const unsigned short* __restrict__ hin,
                                              const unsigned short* __restrict__ m,
                                              const unsigned short* __restrict__ W1t,
                                              const float* __restrict__ B1,
                                              const unsigned short* __restrict__ W2t,
                                              const float* __restrict__ B2,
                                              const float* __restrict__ G,
                                              const float* __restrict__ Bb,
                                              unsigned short* __restrict__ hout,
                                              unsigned char* __restrict__ h8out,
                                              float* __restrict__ out_f32, int N) {
    __shared__ unsigned short P[32][132];   // +4 pad: conflict-light b128 A-frag reads
    __shared__ float s1p[4][32], s2p[4][32];

    int tid = threadIdx.x;
    int w = tid >> 6, lane = tid & 63;
    int quad = lane >> 4, l16 = lane & 15;
    int r0 = blockIdx.x * 32;
    int cs = w * 32;

    // ---- prefetch residual (used after GEMM2; covered by both GEMMs) ----
    unsigned short hvr[2][2][4];
#pragma unroll
    for (int rt = 0; rt < 2; ++rt) {
#pragma unroll
        for (int c = 0; c < 2; ++c) {
            int col = cs + c * 16 + l16;
#pragma unroll
            for (int reg = 0; reg < 4; ++reg) {
                int grow = r0 + rt * 16 + quad * 4 + reg;
                hvr[rt][c][reg] = (grow < N) ? hin[((size_t)grow << 7) + col] : (unsigned short)0;
            }
        }
    }

    // ---- GEMM1: relu(m @ W1 + b1); A direct from global m (same bits as staged) ----
    int ar0 = r0 + l16;
    int ar1 = r0 + 16 + l16;
    bool av0 = ar0 < N, av1 = ar1 < N;
    const unsigned short* ap0 = m + ((size_t)(av0 ? ar0 : 0) << 7) + quad * 8;
    const unsigned short* ap1 = m + ((size_t)(av1 ? ar1 : 0) << 7) + quad * 8;

    f32x4 ac1[2][2];
    ac1[0][0] = (f32x4){0.f, 0.f, 0.f, 0.f}; ac1[0][1] = (f32x4){0.f, 0.f, 0.f, 0.f};
    ac1[1][0] = (f32x4){0.f, 0.f, 0.f, 0.f}; ac1[1][1] = (f32x4){0.f, 0.f, 0.f, 0.f};
#pragma unroll
    for (int k0 = 0; k0 < 128; k0 += 32) {
        s16x8 b0 = *(const s16x8*)(W1t + ((size_t)(cs + l16) << 7) + quad * 8 + k0);
        s16x8 b1 = *(const s16x8*)(W1t + ((size_t)(cs + 16 + l16) << 7) + quad * 8 + k0);
        s16x8 a0 = {0, 0, 0, 0, 0, 0, 0, 0};
        s16x8 a1 = {0, 0, 0, 0, 0, 0, 0, 0};
        if (av0) a0 = *(const s16x8*)(ap0 + k0);
        if (av1) a1 = *(const s16x8*)(ap1 + k0);
        ac1[0][0] = __builtin_amdgcn_mfma_f32_16x16x32_bf16(a0, b0, ac1[0][0], 0, 0, 0);
        ac1[0][1] = __builtin_amdgcn_mfma_f32_16x16x32_bf16(a0, b1, ac1[0][1], 0, 0, 0);
        ac1[1][0] = __builtin_amdgcn_mfma_f32_16x16x32_bf16(a1, b0, ac1[1][0], 0, 0, 0);
        ac1[1][1] = __builtin_amdgcn_mfma_f32_16x16x32_bf16(a1, b1, ac1[1][1], 0, 0, 0);
    }
#pragma unroll
    for (int rt = 0; rt < 2; ++rt) {
#pragma unroll
        for (int c = 0; c < 2; ++c) {
            int col = cs + c * 16 + l16;
            float bv = B1[col];
#pragma unroll
            for (int reg = 0; reg < 4; ++reg) {
                float v = fmaxf(ac1[rt][c][reg] + bv, 0.f);
                P[rt * 16 + quad * 4 + reg][col] = f2bf(v);
            }
        }
    }
    __syncthreads();

    // ---- GEMM2: P @ W2 ----
    f32x4 ac2[2][2];
    ac2[0][0] = (f32x4){0.f, 0.f, 0.f, 0.f}; ac2[0][1] = (f32x4){0.f, 0.f, 0.f, 0.f};
    ac2[1][0] = (f32x4){0.f, 0.f, 0.f, 0.f}; ac2[1][1] = (f32x4){0.f, 0.f, 0.f, 0.f};
#pragma unroll
    for (int k0 = 0; k0 < 128; k0 += 32) {
        s16x8 b0 = *(const s16x8*)(W2t + ((size_t)(cs + l16) << 7) + quad * 8 + k0);
        s16x8 b1 = *(const s16x8*)(W2t + ((size_t)(cs + 16 + l16) << 7) + quad * 8 + k0);
        s16x8 a0 = *(const s16x8*)(&P[l16][quad * 8 + k0]);
        s16x8 a1 = *(const s16x8*)(&P[16 + l16][quad * 8 + k0]);
        ac2[0][0] = __builtin_amdgcn_mfma_f32_16x16x32_bf16(a0, b0, ac2[0][0], 0, 0, 0);
        ac2[0][1] = __builtin_amdgcn_mfma_f32_16x16x32_bf16(a0, b1, ac2[0][1], 0, 0, 0);
        ac2[1][0] = __builtin_amdgcn_mfma_f32_16x16x32_bf16(a1, b0, ac2[1][0], 0, 0, 0);
        ac2[1][1] = __builtin_amdgcn_mfma_f32_16x16x32_bf16(a1, b1, ac2[1][1], 0, 0, 0);
    }

    // ---- epilogue: residual + LN (byte-identical to round-8) ----
    float z[2][2][4];
    float ps1[2][4] = {{0, 0, 0, 0}, {0, 0, 0, 0}};
    float ps2[2][4] = {{0, 0, 0, 0}, {0, 0, 0, 0}};
#pragma unroll
    for (int rt = 0; rt < 2; ++rt) {
#pragma unroll
        for (int c = 0; c < 2; ++c) {
            int col = cs + c * 16 + l16;
            float b2v = B2[col];
#pragma unroll
            for (int reg = 0; reg < 4; ++reg) {
                float hv = bf2f(hvr[rt][c][reg]);
                float zz = ac2[rt][c][reg] + b2v + hv;
                z[rt][c][reg] = zz;
                ps1[rt][reg] += zz;
                ps2[rt][reg] += zz * zz;
            }
        }
    }
#pragma unroll
    for (int off = 1; off < 16; off <<= 1) {
#pragma unroll
        for (int rt = 0; rt < 2; ++rt) {
#pragma unroll
            for (int reg = 0; reg < 4; ++reg) {
                ps1[rt][reg] += __shfl_xor(ps1[rt][reg], off, 64);
                ps2[rt][reg] += __shfl_xor(ps2[rt][reg], off, 64);
            }
        }
    }
    if (l16 == 0) {
#pragma unroll
        for (int rt = 0; rt < 2; ++rt) {
#pragma unroll
            for (int reg = 0; reg < 4; ++reg) {
                s1p[w][rt * 16 + quad * 4 + reg] = ps1[rt][reg];
                s2p[w][rt * 16 + quad * 4 + reg] = ps2[rt][reg];
            }
        }
    }
    __syncthreads();

#pragma unroll
    for (int rt = 0; rt < 2; ++rt) {
#pragma unroll
        for (int reg = 0; reg < 4; ++reg) {
            int row = rt * 16 + quad * 4 + reg;
            float S1 = s1p[0][row] + s1p[1][row] + s1p[2][row] + s1p[3][row];
            float S2 = s2p[0][row] + s2p[1][row] + s2p[2][row] + s2p[3][row];
            float mean = S1 * (1.0f / 128.0f);
            float var = S2 * (1.0f / 128.0f) - mean * mean;
            float rs = rsqrtf(var + LN_EPS);
            int grow = r0 + row;
            if (grow < N) {
#pragma unroll
                for (int c = 0; c < 2; ++c) {
                    int col = cs + c * 16 + l16;
                    float o = (z[rt][c][reg] - mean) * rs * G[col] + Bb[col];
                    if (out_f32) {
                        out_f32[((size_t)grow << 7) + col] = o;   // last layer: f32 only
                    } else {
                        hout[((size_t)grow << 7) + col] = f2bf(o);
                        h8out[((size_t)grow << 7) + col] = f2fp8(o);
                    }
                }
            }
        }
    }
}

// ---------------- launch ----------------

extern "C" void kernel_launch(void* const* d_in, const int* in_sizes, int n_in,
                              void* d_out, int out_size, void* d_ws, size_t ws_size,
                              hipStream_t stream) {
    const float* x    = (const float*)d_in[0];
    const int*   ei   = (const int*)d_in[1];
    const float* in_w = (const float*)d_in[2];
    const float* in_b = (const float*)d_in[3];
    const float* w1   = (const float*)d_in[4];
    const float* b1   = (const float*)d_in[5];
    const float* w2   = (const float*)d_in[6];
    const float* b2   = (const float*)d_in[7];
    const float* ln_g = (const float*)d_in[8];
    const float* ln_b = (const float*)d_in[9];

    const int N = in_sizes[0] / DIM;               // 50000
    const int E = in_sizes[1] / 2;                 // 640000
    const int LAYERS = in_sizes[4] / (DIM * DIM);  // 3

    const int* e_src = ei;
    const int* e_dst = ei + E;

    // workspace layout
    char* ws = (char*)d_ws;
    unsigned short* hb0    = (unsigned short*)ws;  ws += (size_t)N * DIM * 2;
    unsigned short* hb1    = (unsigned short*)ws;  ws += (size_t)N * DIM * 2;
    unsigned char*  h8a    = (unsigned char*)ws;   ws += (size_t)N * DIM;
    unsigned char*  h8b    = (unsigned char*)ws;   ws += (size_t)N * DIM;
    int*            counts = (int*)ws;             ws += (size_t)N * 4;
    int*            rowptr = (int*)ws;             ws += (size_t)(N + 1) * 4;
    int*            cursor = (int*)ws;             ws += (size_t)N * 4;
    float*          dinv   = (float*)ws;           ws += (size_t)N * 4;
    unsigned short* srcidx = (unsigned short*)ws;  ws += (size_t)E * 2;
    unsigned short* wt     = (unsigned short*)ws;  ws += (size_t)(2 * LAYERS + 1) * DIM * DIM * 2;
    unsigned short* mbuf   = (unsigned short*)ws;  ws += (size_t)N * DIM * 2;

    const int nScanBlocks = (N + 1023) / 1024;
    const int nMat = 2 * LAYERS + 1;
    const int nWblk = nMat * 8;

    // --- CSR build + weight cvt + input projection ---
    (void)hipMemsetAsync(counts, 0, (size_t)N * 4, stream);
    prep<<<nWblk + (E + 1023) / 1024, 256, 0, stream>>>(in_w, w1, w2, wt, LAYERS,
                                                        e_dst, E, counts, nWblk);
    scan_all<<<nScanBlocks, 256, 0, stream>>>(counts, N, rowptr, cursor, dinv, E);
    gemm_bias32<<<(N + 31) / 32, 256, 0, stream>>>(x, wt, in_b, hb0, h8a, N);
    fill_csr<<<(E + 1023) / 1024, 256, 0, stream>>>(e_src, e_dst, E, cursor, srcidx);

    const unsigned short* w1t = wt + (size_t)DIM * DIM;
    const unsigned short* w2t = wt + (size_t)(1 + LAYERS) * DIM * DIM;

    // --- layers (ping-pong; gather reads pre-update fp8 table) ---
    int tile_grid = (N + 31) / 32;
    unsigned short* hin  = hb0;  unsigned char* h8in  = h8a;
    unsigned short* hout = hb1;  unsigned char* h8out = h8b;
    for (int i = 0; i < LAYERS; ++i) {
        float* out = (i == LAYERS - 1) ? (float*)d_out : nullptr;
        aggregate<<<tile_grid, 256, 0, stream>>>(h8in, rowptr, srcidx, dinv, mbuf, N);
        mlp_ln<<<tile_grid, 256, 0, stream>>>(hin, mbuf,
                                              w1t + (size_t)i * DIM * DIM, b1 + (size_t)i * DIM,
                                              w2t + (size_t)i * DIM * DIM, b2 + (size_t)i * DIM,
                                              ln_g + (size_t)i * DIM, ln_b + (size_t)i * DIM,
                                              hout, h8out, out, N);
        unsigned short* t = hin; hin = hout; hout = t;
        unsigned char* t8 = h8in; h8in = h8out; h8out = t8;
    }
}

// Round 15
// 315.891 us; speedup vs baseline: 1.0560x; 1.0560x over previous
//
#include <hip/hip_runtime.h>
#include <hip/hip_fp8.h>

#define DIM 128
#define LN_EPS 1e-5f

typedef __attribute__((ext_vector_type(8))) short s16x8;   // 8 bf16 in 4 VGPRs
typedef __attribute__((ext_vector_type(4))) float f32x4;
typedef __attribute__((ext_vector_type(2))) float f32x2;
typedef __attribute__((ext_vector_type(4))) unsigned int u32x4;

__device__ __forceinline__ unsigned short f2bf(float f) {
    unsigned u = __float_as_uint(f);
    unsigned r = u + 0x7fffu + ((u >> 16) & 1u);   // round-to-nearest-even
    return (unsigned short)(r >> 16);
}
__device__ __forceinline__ float bf2f(unsigned short b) {
    return __uint_as_float(((unsigned)b) << 16);
}
__device__ __forceinline__ unsigned char f2fp8(float f) {
    return (unsigned char)__hip_cvt_float_to_fp8(f, __HIP_SATFINITE, __HIP_E4M3);
}
// accumulate 4 fp8 bytes (linear col order) into a[0..3]
__device__ __forceinline__ void acc_fp8x4(float* a, unsigned v) {
    f32x2 lo = __builtin_amdgcn_cvt_pk_f32_fp8(v, false);  // bytes 0,1
    f32x2 hi = __builtin_amdgcn_cvt_pk_f32_fp8(v, true);   // bytes 2,3
    a[0] += lo[0]; a[1] += lo[1]; a[2] += hi[0]; a[3] += hi[1];
}
// accumulate a full u32x4 (16 fp8 bytes) into a[0..15]
__device__ __forceinline__ void acc_fp8x16(float* a, u32x4 v) {
    acc_fp8x4(a + 0,  v[0]);
    acc_fp8x4(a + 4,  v[1]);
    acc_fp8x4(a + 8,  v[2]);
    acc_fp8x4(a + 12, v[3]);
}

// ---------------- prep: weight cvt (f32 -> bf16 transposed) + degree count ----------------

__global__ __launch_bounds__(256) void prep(const float* __restrict__ in_w,
                                            const float* __restrict__ w1,
                                            const float* __restrict__ w2,
                                            unsigned short* __restrict__ wt, int L,
                                            const int* __restrict__ dst, int E,
                                            int* __restrict__ counts, int nWblk) {
    if ((int)blockIdx.x < nWblk) {
        int mat = blockIdx.x >> 3, part = blockIdx.x & 7;
        const float* src;
        if (mat == 0) src = in_w;
        else if (mat <= L) src = w1 + (size_t)(mat - 1) * DIM * DIM;
        else src = w2 + (size_t)(mat - 1 - L) * DIM * DIM;
        unsigned short* dstw = wt + (size_t)mat * DIM * DIM;
        int base = part * 2048 + threadIdx.x;
#pragma unroll
        for (int j = 0; j < 8; ++j) {
            int i = base + j * 256;
            int k = i >> 7, n = i & 127;
            dstw[n * DIM + k] = f2bf(src[i]);
        }
    } else {
        int b = blockIdx.x - nWblk;
        int i = (b * 256 + threadIdx.x) * 4;
        if (i + 3 < E) {
            int4 d = *(const int4*)(dst + i);
            atomicAdd(&counts[d.x], 1);
            atomicAdd(&counts[d.y], 1);
            atomicAdd(&counts[d.z], 1);
            atomicAdd(&counts[d.w], 1);
        } else {
            for (int j = i; j < E; ++j) atomicAdd(&counts[dst[j]], 1);
        }
    }
}

// ---------------- scan (single dispatch): block offset computed in-block ----------------

__global__ __launch_bounds__(256) void scan_all(const int* __restrict__ counts, int n,
                                                int* __restrict__ rowptr,
                                                int* __restrict__ cursor,
                                                float* __restrict__ dinv, int E) {
    __shared__ int wsum[4];
    int tid = threadIdx.x;
    int lane = tid & 63, wid = tid >> 6;

    int limit = blockIdx.x * 1024;            // multiple of 1024
    int acc = 0;
    for (int i = tid * 4; i < limit; i += 1024) {
        int4 c4 = *(const int4*)(counts + i);
        acc += c4.x + c4.y + c4.z + c4.w;
    }
#pragma unroll
    for (int off = 32; off > 0; off >>= 1) acc += __shfl_xor(acc, off, 64);
    if (lane == 0) wsum[wid] = acc;
    __syncthreads();
    int bofs = wsum[0] + wsum[1] + wsum[2] + wsum[3];
    __syncthreads();                          // wsum reused below

    if (blockIdx.x == 0 && tid == 0) rowptr[n] = E;

    int base = blockIdx.x * 1024 + tid * 4;
    int v[4];
#pragma unroll
    for (int j = 0; j < 4; ++j) {
        int i = base + j;
        v[j] = (i < n) ? counts[i] : 0;
    }
    int tsum = v[0] + v[1] + v[2] + v[3];
    int incl = tsum;
#pragma unroll
    for (int off = 1; off < 64; off <<= 1) {
        int t = __shfl_up(incl, off, 64);
        if (lane >= off) incl += t;
    }
    if (lane == 63) wsum[wid] = incl;
    __syncthreads();
    int wofs = 0;
    for (int w = 0; w < 4; ++w)
        if (w < wid) wofs += wsum[w];
    int excl = bofs + wofs + (incl - tsum);
#pragma unroll
    for (int j = 0; j < 4; ++j) {
        int i = base + j;
        if (i < n) {
            rowptr[i] = excl;
            cursor[i] = excl;
            dinv[i] = 1.0f / (float)((v[j] > 1) ? v[j] : 1);
            excl += v[j];
        }
    }
}

// ---------------- CSR fill ----------------

__global__ void fill_csr(const int* __restrict__ src, const int* __restrict__ dst, int E,
                         int* __restrict__ cursor, unsigned short* __restrict__ srcidx) {
    int i = (blockIdx.x * 256 + threadIdx.x) * 4;
    if (i + 3 < E) {
        int4 s4 = *(const int4*)(src + i);
        int4 d4 = *(const int4*)(dst + i);
        int p0 = atomicAdd(&cursor[d4.x], 1); srcidx[p0] = (unsigned short)s4.x;
        int p1 = atomicAdd(&cursor[d4.y], 1); srcidx[p1] = (unsigned short)s4.y;
        int p2 = atomicAdd(&cursor[d4.z], 1); srcidx[p2] = (unsigned short)s4.z;
        int p3 = atomicAdd(&cursor[d4.w], 1); srcidx[p3] = (unsigned short)s4.w;
    } else {
        for (int j = i; j < E; ++j) {
            int p = atomicAdd(&cursor[dst[j]], 1);
            srcidx[p] = (unsigned short)src[j];
        }
    }
}

// ---------------- input projection: 32 rows/block, LDS-transposed epilogue ----------
// (round-10 form, verified bit-exact)

__global__ __launch_bounds__(256) void gemm_bias32(const float* __restrict__ x,
                                                   const unsigned short* __restrict__ Wt,
                                                   const float* __restrict__ bias,
                                                   unsigned short* __restrict__ hb,
                                                   unsigned char* __restrict__ h8, int N) {
    __shared__ __align__(16) unsigned short X[32][136];
    __shared__ __align__(16) float Z[32][132];
    __shared__ __align__(16) float bias_s[128];

    int tid = threadIdx.x;
    int w = tid >> 6, lane = tid & 63;
    int quad = lane >> 4, l16 = lane & 15;
    int r0 = blockIdx.x * 32;
    int cs = w * 32;

    // ---- stage bias (128 f32) ----
    if (tid < 32) *(float4*)(bias_s + tid * 4) = *(const float4*)(bias + tid * 4);

    // ---- stage x tile: thread covers row (tid>>3), cols [(tid&7)*16, +16) ----
    {
        int row = tid >> 3;
        int c0 = (tid & 7) * 16;
        int grow = r0 + row;
        u32x4 o0 = {0, 0, 0, 0}, o1 = {0, 0, 0, 0};
        if (grow < N) {
            const float4* xp = (const float4*)(x + ((size_t)grow << 7) + c0);
            float4 f0 = xp[0], f1 = xp[1], f2 = xp[2], f3 = xp[3];
            o0[0] = (unsigned)f2bf(f0.x) | ((unsigned)f2bf(f0.y) << 16);
            o0[1] = (unsigned)f2bf(f0.z) | ((unsigned)f2bf(f0.w) << 16);
            o0[2] = (unsigned)f2bf(f1.x) | ((unsigned)f2bf(f1.y) << 16);
            o0[3] = (unsigned)f2bf(f1.z) | ((unsigned)f2bf(f1.w) << 16);
            o1[0] = (unsigned)f2bf(f2.x) | ((unsigned)f2bf(f2.y) << 16);
            o1[1] = (unsigned)f2bf(f2.z) | ((unsigned)f2bf(f2.w) << 16);
            o1[2] = (unsigned)f2bf(f3.x) | ((unsigned)f2bf(f3.y) << 16);
            o1[3] = (unsigned)f2bf(f3.z) | ((unsigned)f2bf(f3.w) << 16);
        }
        *(u32x4*)(&X[row][c0])     = o0;
        *(u32x4*)(&X[row][c0 + 8]) = o1;
    }
    __syncthreads();

    // ---- GEMM: wave computes 32 rows x 32 cols, B-frags shared ----
    f32x4 ac[2][2];
    ac[0][0] = (f32x4){0.f, 0.f, 0.f, 0.f}; ac[0][1] = (f32x4){0.f, 0.f, 0.f, 0.f};
    ac[1][0] = (f32x4){0.f, 0.f, 0.f, 0.f}; ac[1][1] = (f32x4){0.f, 0.f, 0.f, 0.f};
#pragma unroll
    for (int k0 = 0; k0 < 128; k0 += 32) {
        s16x8 b0 = *(const s16x8*)(Wt + ((size_t)(cs + l16) << 7) + quad * 8 + k0);
        s16x8 b1 = *(const s16x8*)(Wt + ((size_t)(cs + 16 + l16) << 7) + quad * 8 + k0);
        s16x8 a0 = *(const s16x8*)(&X[l16][quad * 8 + k0]);
        s16x8 a1 = *(const s16x8*)(&X[16 + l16][quad * 8 + k0]);
        ac[0][0] = __builtin_amdgcn_mfma_f32_16x16x32_bf16(a0, b0, ac[0][0], 0, 0, 0);
        ac[0][1] = __builtin_amdgcn_mfma_f32_16x16x32_bf16(a0, b1, ac[0][1], 0, 0, 0);
        ac[1][0] = __builtin_amdgcn_mfma_f32_16x16x32_bf16(a1, b0, ac[1][0], 0, 0, 0);
        ac[1][1] = __builtin_amdgcn_mfma_f32_16x16x32_bf16(a1, b1, ac[1][1], 0, 0, 0);
    }

    // ---- dump acc+bias to LDS Z (fragment scatter stays in LDS) ----
#pragma unroll
    for (int rt = 0; rt < 2; ++rt) {
#pragma unroll
        for (int c = 0; c < 2; ++c) {
            int col = cs + c * 16 + l16;
            float bv = bias_s[col];
#pragma unroll
            for (int reg = 0; reg < 4; ++reg) {
                Z[rt * 16 + quad * 4 + reg][col] = ac[rt][c][reg] + bv;
            }
        }
    }
    __syncthreads();

    // ---- pass 2: row-contiguous vector stores ----
    {
        int row = tid >> 3;
        int c0 = (tid & 7) * 16;
        int grow = r0 + row;
        if (grow < N) {
            u32x4 ob0, ob1, o8;
#pragma unroll
            for (int j = 0; j < 4; ++j) {
                float v0 = Z[row][c0 + 2 * j];
                float v1 = Z[row][c0 + 2 * j + 1];
                float v2 = Z[row][c0 + 8 + 2 * j];
                float v3 = Z[row][c0 + 8 + 2 * j + 1];
                ob0[j] = (unsigned)f2bf(v0) | ((unsigned)f2bf(v1) << 16);
                ob1[j] = (unsigned)f2bf(v2) | ((unsigned)f2bf(v3) << 16);
                float w0 = Z[row][c0 + 4 * j], w1 = Z[row][c0 + 4 * j + 1];
                float w2 = Z[row][c0 + 4 * j + 2], w3 = Z[row][c0 + 4 * j + 3];
                o8[j] = (unsigned)f2fp8(w0) | ((unsigned)f2fp8(w1) << 8)
                      | ((unsigned)f2fp8(w2) << 16) | ((unsigned)f2fp8(w3) << 24);
            }
            *(u32x4*)(hb + ((size_t)grow << 7) + c0)     = ob0;
            *(u32x4*)(hb + ((size_t)grow << 7) + c0 + 8) = ob1;
            *(u32x4*)(h8 + ((size_t)grow << 7) + c0)     = o8;
        }
    }
}

// ---------------- aggregation-only kernel (round-4 form, ushort srcidx) ----------------

__global__ __launch_bounds__(256) void aggregate(const unsigned char* __restrict__ h8in,
                                                 const int* __restrict__ rowptr,
                                                 const unsigned short* __restrict__ srcidx,
                                                 const float* __restrict__ dinv,
                                                 unsigned short* __restrict__ mout, int N) {
    int tid = threadIdx.x;
    int w = tid >> 6, lane = tid & 63;
    int g = lane >> 3, li = lane & 7;
    int nd = blockIdx.x * 32 + w * 8 + g;
    bool nv = nd < N;

    int e  = nv ? rowptr[nd] : 0;
    int ee = nv ? rowptr[nd + 1] : 0;
    float di = nv ? dinv[nd] : 0.f;

    const unsigned char* hsl = h8in + li * 16;   // lane's 16-B slice of a row

    float a[16];
#pragma unroll
    for (int j = 0; j < 16; ++j) a[j] = 0.f;

#define GIDX(jj) (((jj) < ee) ? (int)srcidx[(jj)] : -1)
    int jA = e;
    int iA0 = GIDX(jA + 0), iA1 = GIDX(jA + 1), iA2 = GIDX(jA + 2), iA3 = GIDX(jA + 3);
    u32x4 A0 = {0, 0, 0, 0}, A1 = {0, 0, 0, 0}, A2 = {0, 0, 0, 0}, A3 = {0, 0, 0, 0};
    if (iA0 >= 0) A0 = *(const u32x4*)(hsl + ((size_t)iA0 << 7));
    if (iA1 >= 0) A1 = *(const u32x4*)(hsl + ((size_t)iA1 << 7));
    if (iA2 >= 0) A2 = *(const u32x4*)(hsl + ((size_t)iA2 << 7));
    if (iA3 >= 0) A3 = *(const u32x4*)(hsl + ((size_t)iA3 << 7));
    int jB = jA + 4;
    int iB0 = GIDX(jB + 0), iB1 = GIDX(jB + 1), iB2 = GIDX(jB + 2), iB3 = GIDX(jB + 3);

    while (__any(jA < ee)) {
        u32x4 B0 = {0, 0, 0, 0}, B1v = {0, 0, 0, 0}, B2v = {0, 0, 0, 0}, B3 = {0, 0, 0, 0};
        if (iB0 >= 0) B0  = *(const u32x4*)(hsl + ((size_t)iB0 << 7));
        if (iB1 >= 0) B1v = *(const u32x4*)(hsl + ((size_t)iB1 << 7));
        if (iB2 >= 0) B2v = *(const u32x4*)(hsl + ((size_t)iB2 << 7));
        if (iB3 >= 0) B3  = *(const u32x4*)(hsl + ((size_t)iB3 << 7));
        int jC = jB + 4;
        int iC0 = GIDX(jC + 0), iC1 = GIDX(jC + 1), iC2 = GIDX(jC + 2), iC3 = GIDX(jC + 3);
        acc_fp8x16(a, A0);
        acc_fp8x16(a, A1);
        acc_fp8x16(a, A2);
        acc_fp8x16(a, A3);
        jA = jB; A0 = B0; A1 = B1v; A2 = B2v; A3 = B3;
        jB = jC; iB0 = iC0; iB1 = iC1; iB2 = iC2; iB3 = iC3;
    }
#undef GIDX

    if (nv) {
        u32x4 o0, o1;
#pragma unroll
        for (int j = 0; j < 4; ++j) {
            unsigned lo0 = f2bf(a[2 * j]     * di);
            unsigned hi0 = f2bf(a[2 * j + 1] * di);
            o0[j] = lo0 | (hi0 << 16);
            unsigned lo1 = f2bf(a[8 + 2 * j]     * di);
            unsigned hi1 = f2bf(a[8 + 2 * j + 1] * di);
            o1[j] = lo1 | (hi1 << 16);
        }
        unsigned short* mp = mout + ((size_t)nd << 7) + li * 16;
        *(u32x4*)(mp)     = o0;
        *(u32x4*)(mp + 8) = o1;
    }
}

// ---------------- MLP + LN: direct-global A (r13) + LDS-routed epilogue (r11) -------
// Both edits independently verified bit-exact vs round-8:
//   GEMM1 A-fragments read directly from global m (contiguous 16B/lane, same bits
//   as the staged path) -> m tile + its barrier gone.
//   Residual staged row-contiguous -> R; LN arithmetic identical r8 (same
//   association, same butterfly, same final sum); outputs routed through LDS Z
//   (exact f32) -> row-contiguous vector stores.
// Z aliases P|R (both dead after the s1p barrier). Barriers: 3. LDS: 17.9 KB.

__global__ __launch_bounds__(256) void mlp_ln(const unsigned short* __restrict__ hin,
                                              const unsigned short* __restrict__ m,
                                              const unsigned short* __restrict__ W1t,
                                              const float* __restrict__ B1,
                                              const unsigned short* __restrict__ W2t,
                                              const float* __restrict__ B2,
                                              const float* __restrict__ G,
                                              const float* __restrict__ Bb,
                                              unsigned short* __restrict__ hout,
                                              unsigned char* __restrict__ h8out,
                                              float* __restrict__ out_f32, int N) {
    __shared__ __align__(16) char raw[17920];
    unsigned short (*P)[132] = (unsigned short (*)[132])raw;            // 0..8448
    unsigned short (*R)[132] = (unsigned short (*)[132])(raw + 8448);   // 8448..16896
    float (*Z)[132] = (float (*)[132])raw;                              // aliases P|R (after s1p sync)
    float (*s1p)[32] = (float (*)[32])(raw + 16896);                    // 16896..17408
    float (*s2p)[32] = (float (*)[32])(raw + 17408);                    // 17408..17920

    int tid = threadIdx.x;
    int w = tid >> 6, lane = tid & 63;
    int quad = lane >> 4, l16 = lane & 15;
    int r0 = blockIdx.x * 32;
    int cs = w * 32;
    int prow = tid >> 3;            // pass-2 row (0..31)
    int pc0 = (tid & 7) * 16;       // pass-2 col base

    // ---- stage residual tile row-contiguous -> R (same bits as scalar loads) ----
    {
        int grow = r0 + prow;
        u32x4 h0 = {0, 0, 0, 0}, h1 = {0, 0, 0, 0};
        if (grow < N) {
            h0 = *(const u32x4*)(hin + ((size_t)grow << 7) + pc0);
            h1 = *(const u32x4*)(hin + ((size_t)grow << 7) + pc0 + 8);
        }
        *(u32x4*)(&R[prow][pc0])     = h0;
        *(u32x4*)(&R[prow][pc0 + 8]) = h1;
    }

    // ---- GEMM1: relu(m @ W1 + b1); A direct from global m (same bits as staged) ----
    int ar0 = r0 + l16;
    int ar1 = r0 + 16 + l16;
    bool av0 = ar0 < N, av1 = ar1 < N;
    const unsigned short* ap0 = m + ((size_t)(av0 ? ar0 : 0) << 7) + quad * 8;
    const unsigned short* ap1 = m + ((size_t)(av1 ? ar1 : 0) << 7) + quad * 8;

    f32x4 ac1[2][2];
    ac1[0][0] = (f32x4){0.f, 0.f, 0.f, 0.f}; ac1[0][1] = (f32x4){0.f, 0.f, 0.f, 0.f};
    ac1[1][0] = (f32x4){0.f, 0.f, 0.f, 0.f}; ac1[1][1] = (f32x4){0.f, 0.f, 0.f, 0.f};
#pragma unroll
    for (int k0 = 0; k0 < 128; k0 += 32) {
        s16x8 b0 = *(const s16x8*)(W1t + ((size_t)(cs + l16) << 7) + quad * 8 + k0);
        s16x8 b1 = *(const s16x8*)(W1t + ((size_t)(cs + 16 + l16) << 7) + quad * 8 + k0);
        s16x8 a0 = {0, 0, 0, 0, 0, 0, 0, 0};
        s16x8 a1 = {0, 0, 0, 0, 0, 0, 0, 0};
        if (av0) a0 = *(const s16x8*)(ap0 + k0);
        if (av1) a1 = *(const s16x8*)(ap1 + k0);
        ac1[0][0] = __builtin_amdgcn_mfma_f32_16x16x32_bf16(a0, b0, ac1[0][0], 0, 0, 0);
        ac1[0][1] = __builtin_amdgcn_mfma_f32_16x16x32_bf16(a0, b1, ac1[0][1], 0, 0, 0);
        ac1[1][0] = __builtin_amdgcn_mfma_f32_16x16x32_bf16(a1, b0, ac1[1][0], 0, 0, 0);
        ac1[1][1] = __builtin_amdgcn_mfma_f32_16x16x32_bf16(a1, b1, ac1[1][1], 0, 0, 0);
    }
#pragma unroll
    for (int rt = 0; rt < 2; ++rt) {
#pragma unroll
        for (int c = 0; c < 2; ++c) {
            int col = cs + c * 16 + l16;
            float bv = B1[col];
#pragma unroll
            for (int reg = 0; reg < 4; ++reg) {
                float v = fmaxf(ac1[rt][c][reg] + bv, 0.f);
                P[rt * 16 + quad * 4 + reg][col] = f2bf(v);
            }
        }
    }
    __syncthreads();   // covers P writes AND R staging

    // ---- GEMM2: P @ W2 ----
    f32x4 ac2[2][2];
    ac2[0][0] = (f32x4){0.f, 0.f, 0.f, 0.f}; ac2[0][1] = (f32x4){0.f, 0.f, 0.f, 0.f};
    ac2[1][0] = (f32x4){0.f, 0.f, 0.f, 0.f}; ac2[1][1] = (f32x4){0.f, 0.f, 0.f, 0.f};
#pragma unroll
    for (int k0 = 0; k0 < 128; k0 += 32) {
        s16x8 b0 = *(const s16x8*)(W2t + ((size_t)(cs + l16) << 7) + quad * 8 + k0);
        s16x8 b1 = *(const s16x8*)(W2t + ((size_t)(cs + 16 + l16) << 7) + quad * 8 + k0);
        s16x8 a0 = *(const s16x8*)(&P[l16][quad * 8 + k0]);
        s16x8 a1 = *(const s16x8*)(&P[16 + l16][quad * 8 + k0]);
        ac2[0][0] = __builtin_amdgcn_mfma_f32_16x16x32_bf16(a0, b0, ac2[0][0], 0, 0, 0);
        ac2[0][1] = __builtin_amdgcn_mfma_f32_16x16x32_bf16(a0, b1, ac2[0][1], 0, 0, 0);
        ac2[1][0] = __builtin_amdgcn_mfma_f32_16x16x32_bf16(a1, b0, ac2[1][0], 0, 0, 0);
        ac2[1][1] = __builtin_amdgcn_mfma_f32_16x16x32_bf16(a1, b1, ac2[1][1], 0, 0, 0);
    }

    // ---- epilogue: residual + LN — arithmetic IDENTICAL to round-8 ----
    float z[2][2][4];
    float ps1[2][4] = {{0, 0, 0, 0}, {0, 0, 0, 0}};
    float ps2[2][4] = {{0, 0, 0, 0}, {0, 0, 0, 0}};
#pragma unroll
    for (int rt = 0; rt < 2; ++rt) {
#pragma unroll
        for (int c = 0; c < 2; ++c) {
            int col = cs + c * 16 + l16;
            float b2v = B2[col];
#pragma unroll
            for (int reg = 0; reg < 4; ++reg) {
                float hv = bf2f(R[rt * 16 + quad * 4 + reg][col]);   // same bits as global read
                float zz = ac2[rt][c][reg] + b2v + hv;
                z[rt][c][reg] = zz;
                ps1[rt][reg] += zz;
                ps2[rt][reg] += zz * zz;
            }
        }
    }
#pragma unroll
    for (int off = 1; off < 16; off <<= 1) {
#pragma unroll
        for (int rt = 0; rt < 2; ++rt) {
#pragma unroll
            for (int reg = 0; reg < 4; ++reg) {
                ps1[rt][reg] += __shfl_xor(ps1[rt][reg], off, 64);
                ps2[rt][reg] += __shfl_xor(ps2[rt][reg], off, 64);
            }
        }
    }
    if (l16 == 0) {
#pragma unroll
        for (int rt = 0; rt < 2; ++rt) {
#pragma unroll
            for (int reg = 0; reg < 4; ++reg) {
                s1p[w][rt * 16 + quad * 4 + reg] = ps1[rt][reg];
                s2p[w][rt * 16 + quad * 4 + reg] = ps2[rt][reg];
            }
        }
    }
    __syncthreads();   // all waves past GEMM2 + R reads -> P|R dead -> Z writable

#pragma unroll
    for (int rt = 0; rt < 2; ++rt) {
#pragma unroll
        for (int reg = 0; reg < 4; ++reg) {
            int row = rt * 16 + quad * 4 + reg;
            float S1 = s1p[0][row] + s1p[1][row] + s1p[2][row] + s1p[3][row];
            float S2 = s2p[0][row] + s2p[1][row] + s2p[2][row] + s2p[3][row];
            float mean = S1 * (1.0f / 128.0f);
            float var = S2 * (1.0f / 128.0f) - mean * mean;
            float rs = rsqrtf(var + LN_EPS);
#pragma unroll
            for (int c = 0; c < 2; ++c) {
                int col = cs + c * 16 + l16;
                float o = (z[rt][c][reg] - mean) * rs * G[col] + Bb[col];  // same expr as r8
                Z[row][col] = o;   // exact f32 routed through LDS
            }
        }
    }
    __syncthreads();

    // ---- pass 2: row-contiguous vector stores (same rounding fns on same values) ----
    {
        int grow = r0 + prow;
        if (grow < N) {
            if (out_f32) {
                float* op = out_f32 + ((size_t)grow << 7) + pc0;
#pragma unroll
                for (int jj = 0; jj < 4; ++jj) {
                    f32x4 o4 = {Z[prow][pc0 + jj * 4], Z[prow][pc0 + jj * 4 + 1],
                                Z[prow][pc0 + jj * 4 + 2], Z[prow][pc0 + jj * 4 + 3]};
                    *(f32x4*)(op + jj * 4) = o4;
                }
            } else {
                u32x4 ob0, ob1, o8;
#pragma unroll
                for (int j = 0; j < 4; ++j) {
                    float v0 = Z[prow][pc0 + 2 * j];
                    float v1 = Z[prow][pc0 + 2 * j + 1];
                    float v2 = Z[prow][pc0 + 8 + 2 * j];
                    float v3 = Z[prow][pc0 + 8 + 2 * j + 1];
                    ob0[j] = (unsigned)f2bf(v0) | ((unsigned)f2bf(v1) << 16);
                    ob1[j] = (unsigned)f2bf(v2) | ((unsigned)f2bf(v3) << 16);
                    float w0 = Z[prow][pc0 + 4 * j], w1 = Z[prow][pc0 + 4 * j + 1];
                    float w2 = Z[prow][pc0 + 4 * j + 2], w3 = Z[prow][pc0 + 4 * j + 3];
                    o8[j] = (unsigned)f2fp8(w0) | ((unsigned)f2fp8(w1) << 8)
                          | ((unsigned)f2fp8(w2) << 16) | ((unsigned)f2fp8(w3) << 24);
                }
                *(u32x4*)(hout + ((size_t)grow << 7) + pc0)     = ob0;
                *(u32x4*)(hout + ((size_t)grow << 7) + pc0 + 8) = ob1;
                *(u32x4*)(h8out + ((size_t)grow << 7) + pc0)    = o8;
            }
        }
    }
}

// ---------------- launch ----------------

extern "C" void kernel_launch(void* const* d_in, const int* in_sizes, int n_in,
                              void* d_out, int out_size, void* d_ws, size_t ws_size,
                              hipStream_t stream) {
    const float* x    = (const float*)d_in[0];
    const int*   ei   = (const int*)d_in[1];
    const float* in_w = (const float*)d_in[2];
    const float* in_b = (const float*)d_in[3];
    const float* w1   = (const float*)d_in[4];
    const float* b1   = (const float*)d_in[5];
    const float* w2   = (const float*)d_in[6];
    const float* b2   = (const float*)d_in[7];
    const float* ln_g = (const float*)d_in[8];
    const float* ln_b = (const float*)d_in[9];

    const int N = in_sizes[0] / DIM;               // 50000
    const int E = in_sizes[1] / 2;                 // 640000
    const int LAYERS = in_sizes[4] / (DIM * DIM);  // 3

    const int* e_src = ei;
    const int* e_dst = ei + E;

    // workspace layout
    char* ws = (char*)d_ws;
    unsigned short* hb0    = (unsigned short*)ws;  ws += (size_t)N * DIM * 2;
    unsigned short* hb1    = (unsigned short*)ws;  ws += (size_t)N * DIM * 2;
    unsigned char*  h8a    = (unsigned char*)ws;   ws += (size_t)N * DIM;
    unsigned char*  h8b    = (unsigned char*)ws;   ws += (size_t)N * DIM;
    int*            counts = (int*)ws;             ws += (size_t)N * 4;
    int*            rowptr = (int*)ws;             ws += (size_t)(N + 1) * 4;
    int*            cursor = (int*)ws;             ws += (size_t)N * 4;
    float*          dinv   = (float*)ws;           ws += (size_t)N * 4;
    unsigned short* srcidx = (unsigned short*)ws;  ws += (size_t)E * 2;
    unsigned short* wt     = (unsigned short*)ws;  ws += (size_t)(2 * LAYERS + 1) * DIM * DIM * 2;
    unsigned short* mbuf   = (unsigned short*)ws;  ws += (size_t)N * DIM * 2;

    const int nScanBlocks = (N + 1023) / 1024;
    const int nMat = 2 * LAYERS + 1;
    const int nWblk = nMat * 8;

    // --- CSR build + weight cvt + input projection ---
    (void)hipMemsetAsync(counts, 0, (size_t)N * 4, stream);
    prep<<<nWblk + (E + 1023) / 1024, 256, 0, stream>>>(in_w, w1, w2, wt, LAYERS,
                                                        e_dst, E, counts, nWblk);
    scan_all<<<nScanBlocks, 256, 0, stream>>>(counts, N, rowptr, cursor, dinv, E);
    gemm_bias32<<<(N + 31) / 32, 256, 0, stream>>>(x, wt, in_b, hb0, h8a, N);
    fill_csr<<<(E + 1023) / 1024, 256, 0, stream>>>(e_src, e_dst, E, cursor, srcidx);

    const unsigned short* w1t = wt + (size_t)DIM * DIM;
    const unsigned short* w2t = wt + (size_t)(1 + LAYERS) * DIM * DIM;

    // --- layers (ping-pong; gather reads pre-update fp8 table) ---
    int tile_grid = (N + 31) / 32;
    unsigned short* hin  = hb0;  unsigned char* h8in  = h8a;
    unsigned short* hout = hb1;  unsigned char* h8out = h8b;
    for (int i = 0; i < LAYERS; ++i) {
        float* out = (i == LAYERS - 1) ? (float*)d_out : nullptr;
        aggregate<<<tile_grid, 256, 0, stream>>>(h8in, rowptr, srcidx, dinv, mbuf, N);
        mlp_ln<<<tile_grid, 256, 0, stream>>>(hin, mbuf,
                                              w1t + (size_t)i * DIM * DIM, b1 + (size_t)i * DIM,
                                              w2t + (size_t)i * DIM * DIM, b2 + (size_t)i * DIM,
                                              ln_g + (size_t)i * DIM, ln_b + (size_t)i * DIM,
                                              hout, h8out, out, N);
        unsigned short* t = hin; hin = hout; hout = t;
        unsigned char* t8 = h8in; h8in = h8out; h8out = t8;
    }
}